// Round 8
// baseline (412.614 us; speedup 1.0000x reference)
//
#include <hip/hip_runtime.h>
#include <stdint.h>

// Problem: DynamicVoxelizer. B=8, N=1e6, voxel=0.2, grid (x,y,z)=(512,512,30).
// d_out = FLOAT32 x 88,000,000, concatenated:
//   [0,24M) out_points  [24M,48M) coords_zyx  [48M,56M) idx
//   [56M,80M) offsets   [80M,88M) valid
// History: R3 424us -> R6 LDS-coalesced stores 407 -> R7 strided remap 405
// (neutral). Model: ~315-330us fixed harness fills + kernel ~75-95us vs 71us
// mandatory floor. R8: occupancy probe — PPB=512, ALL five regions staged in
// LDS (22KB -> 7 blocks/CU = 28 waves/CU vs 16), every store a full-line fx4,
// no bounds guards (8M = 512 * 15625 exactly).

#define NPB   1000000
#define TOT   8000000
#define BLK   256
#define PPT   2
#define PPB   (BLK * PPT)        // 512 points per block
#define NBLK  (TOT / PPB)        // 15625, exact

typedef float fx4 __attribute__((ext_vector_type(4)));

__global__ __launch_bounds__(256) void voxelize_kernel(
        const float* __restrict__ pts, float* __restrict__ out) {
    __shared__ float lsA[PPB * 3];   // out_points   6 KB
    __shared__ float lsB[PPB * 3];   // coords_zyx   6 KB
    __shared__ float lsC[PPB * 3];   // offsets      6 KB
    __shared__ float lsD[PPB];       // idx          2 KB
    __shared__ float lsE[PPB];       // valid        2 KB

    int t = threadIdx.x;
    uint32_t P0 = (uint32_t)blockIdx.x * PPB;

#pragma unroll
    for (int j = 0; j < PPT; ++j) {
        int      pb = j * BLK + t;       // point index within block
        uint32_t n  = P0 + pb;           // global point index (< TOT always)
        uint32_t b  = n / NPB;           // magic-mul
        uint32_t ni = n - b * NPB;       // index within batch

        // 12B/lane contiguous load (dwordx3)
        const float* pp = pts + (size_t)n * 3;
        float x = pp[0], y = pp[1], z = pp[2];

        bool nn = (x == x) && (y == y) && (z == z);
        float px = nn ? x : 0.0f;
        float py = nn ? y : 0.0f;
        float pz = nn ? z : 0.0f;
        // Exact numpy fp32 sequence: (p - min)/vs, floor, int cast.
        // Division must stay a division (x*5.0f flips voxel boundaries).
        float tx = (px + 51.2f) / 0.2f;
        float ty = (py + 51.2f) / 0.2f;
        float tz = (pz + 3.0f)  / 0.2f;
        int cx = (int)floorf(tx);
        int cy = (int)floorf(ty);
        int cz = (int)floorf(tz);
        bool valid = nn && (cx >= 0) && (cx < 512)
                        && (cy >= 0) && (cy < 512)
                        && (cz >= 0) && (cz < 30);
        float ctx = ((float)cx * 0.2f + (-51.2f)) + 0.1f;
        float cty = ((float)cy * 0.2f + (-51.2f)) + 0.1f;
        float ctz = ((float)cz * 0.2f + (-3.0f))  + 0.1f;

        lsA[3*pb+0] = valid ? px : 0.0f;
        lsA[3*pb+1] = valid ? py : 0.0f;
        lsA[3*pb+2] = valid ? pz : 0.0f;
        lsB[3*pb+0] = valid ? (float)cz : -1.0f;   // zyx order
        lsB[3*pb+1] = valid ? (float)cy : -1.0f;
        lsB[3*pb+2] = valid ? (float)cx : -1.0f;
        lsC[3*pb+0] = valid ? (px - ctx) : 0.0f;
        lsC[3*pb+1] = valid ? (py - cty) : 0.0f;
        lsC[3*pb+2] = valid ? (pz - ctz) : 0.0f;
        lsD[pb] = valid ? (float)ni : -1.0f;
        lsE[pb] = valid ? 1.0f : 0.0f;
    }

    __syncthreads();

    // Cooperative full-line fx4 stores. Vec3 regions: 384 fx4/block each.
    size_t f40 = (size_t)blockIdx.x * (PPB * 3 / 4);   // *384
    {
        int li = t;                                    // 0..255
        ((fx4*)(out))[f40 + li]                    = ((const fx4*)lsA)[li];
        ((fx4*)(out + (size_t)24000000))[f40 + li] = ((const fx4*)lsB)[li];
        ((fx4*)(out + (size_t)56000000))[f40 + li] = ((const fx4*)lsC)[li];
    }
    if (t < 128) {                                     // li = 256..383
        int li = 256 + t;
        ((fx4*)(out))[f40 + li]                    = ((const fx4*)lsA)[li];
        ((fx4*)(out + (size_t)24000000))[f40 + li] = ((const fx4*)lsB)[li];
        ((fx4*)(out + (size_t)56000000))[f40 + li] = ((const fx4*)lsC)[li];
    } else {
        // Scalar regions: 128 fx4/block each; waves 2-3 handle them
        // (wave-uniform region selection, no divergence within a wave pair).
        int li = t - 128;                              // 0..127
        size_t f4s = (size_t)blockIdx.x * (PPB / 4);   // *128
        ((fx4*)(out + (size_t)48000000))[f4s + li] = ((const fx4*)lsD)[li];
        ((fx4*)(out + (size_t)80000000))[f4s + li] = ((const fx4*)lsE)[li];
    }
}

extern "C" void kernel_launch(void* const* d_in, const int* in_sizes, int n_in,
                              void* d_out, int out_size, void* d_ws, size_t ws_size,
                              hipStream_t stream) {
    const float* pts = (const float*)d_in[0];
    float* out = (float*)d_out;
    voxelize_kernel<<<NBLK, BLK, 0, stream>>>(pts, out);
}